// Round 1
// baseline (303.875 us; speedup 1.0000x reference)
//
#include <hip/hip_runtime.h>
#include <math.h>

#define EPSF 1e-6f
#define NB    1024
#define ND    512
#define NCAND 40000
#define NPAD  40064          // 313 * 128
#define NCHUNK 626           // NPAD / 64 : one partial per (row, 64-col chunk)

typedef __attribute__((ext_vector_type(8))) short          bf16x8;
typedef __attribute__((ext_vector_type(8))) unsigned short ushort8;
typedef __attribute__((ext_vector_type(4))) float          f32x4;

// ---------- helpers ----------
__device__ __forceinline__ unsigned short f2bf(float f) {
  union { float f; unsigned int u; } v; v.f = f;
  unsigned int u = v.u;
  return (unsigned short)((u + 0x7FFFu + ((u >> 16) & 1u)) >> 16);  // RNE
}

__device__ __forceinline__ void gload_lds16(const void* g, void* l) {
  __builtin_amdgcn_global_load_lds(
      (const __attribute__((address_space(1))) void*)g,
      (__attribute__((address_space(3))) void*)l, 16, 0, 0);
}

// ---------- prep: fp32 -> bf16 rows + sum-of-squares (exact fp32) ----------
// one wave per row; 4 rows per 256-thread block
__global__ __launch_bounds__(256) void prep_kernel(
    const float* __restrict__ src, unsigned short* __restrict__ dst,
    float* __restrict__ sq, int nfull, int npad)
{
  const int wid = threadIdx.x >> 6, lane = threadIdx.x & 63;
  const long row = (long)blockIdx.x * 4 + wid;
  if (row >= npad) return;
  float vals[8];
  if (row < nfull) {
    const float4* s = (const float4*)(src + row * ND + lane * 8);
    float4 a = s[0], b = s[1];
    vals[0]=a.x; vals[1]=a.y; vals[2]=a.z; vals[3]=a.w;
    vals[4]=b.x; vals[5]=b.y; vals[6]=b.z; vals[7]=b.w;
  } else {
    #pragma unroll
    for (int i = 0; i < 8; ++i) vals[i] = 0.f;
  }
  float ss = 0.f;
  ushort8 o;
  #pragma unroll
  for (int i = 0; i < 8; ++i) { ss = fmaf(vals[i], vals[i], ss); o[i] = f2bf(vals[i]); }
  *(ushort8*)(dst + row * ND + lane * 8) = o;
  #pragma unroll
  for (int m = 1; m < 64; m <<= 1) ss += __shfl_xor(ss, m, 64);
  if (lane == 0) sq[row] = ss;
}

// ---------- exact fp32 target logit, one wave per row ----------
__global__ __launch_bounds__(64) void tgt_kernel(
    const float* __restrict__ q, const float* __restrict__ cand,
    const float* __restrict__ bias, const float* __restrict__ curv,
    const int* __restrict__ target, float* __restrict__ tgtl)
{
  const int b = blockIdx.x, lane = threadIdx.x;
  const int t = target[b];
  const float4* qp = (const float4*)(q + (long)b * ND + lane * 8);
  const float4* cp = (const float4*)(cand + (long)t * ND + lane * 8);
  float4 a0 = qp[0], a1 = qp[1], c0 = cp[0], c1 = cp[1];
  float qa[8] = {a0.x,a0.y,a0.z,a0.w,a1.x,a1.y,a1.z,a1.w};
  float ca[8] = {c0.x,c0.y,c0.z,c0.w,c1.x,c1.y,c1.z,c1.w};
  float xy = 0.f, xs = 0.f, ys = 0.f;
  #pragma unroll
  for (int i = 0; i < 8; ++i) {
    xy = fmaf(qa[i], ca[i], xy);
    xs = fmaf(qa[i], qa[i], xs);
    ys = fmaf(ca[i], ca[i], ys);
  }
  #pragma unroll
  for (int m = 1; m < 64; m <<= 1) {
    xy += __shfl_xor(xy, m, 64);
    xs += __shfl_xor(xs, m, 64);
    ys += __shfl_xor(ys, m, 64);
  }
  if (lane == 0) {
    float c  = curv[b];
    float sc = sqrtf(c + EPSF);
    float A  = 1.f - 2.f * c * xy + c * ys;
    float Bc = 1.f - c * xs;
    float nsq = A * A * xs - 2.f * A * Bc * xy + Bc * Bc * ys;
    float den = 1.f - 2.f * c * xy + c * c * xs * ys;
    float dn  = sqrtf(fmaxf(nsq, 0.f)) / (den + EPSF);
    dn = fminf(fmaxf(dn, EPSF), 1.f / (sc + EPSF) - EPSF);
    float tt  = fminf(sc * dn, 1.f - EPSF);
    float dist = 2.f / (sc + EPSF) * atanhf(tt);
    tgtl[b] = bias[t] - dist;
  }
}

// ---------- fused bf16 GEMM + hyperbolic epilogue + partial expsum ----------
// 128x128 tile, BK=64, 256 threads (4 waves in 2x2), 4x4 frags of 16x16x32
__global__ __launch_bounds__(256) void gemm_epi_kernel(
    const unsigned short* __restrict__ Qb,   // [NB][ND] bf16
    const unsigned short* __restrict__ Cb,   // [NPAD][ND] bf16
    const float* __restrict__ xsq, const float* __restrict__ ysq,
    const float* __restrict__ curv, const float* __restrict__ bias,
    float* __restrict__ partials)            // [NB][NCHUNK]
{
  __shared__ unsigned short As[128 * 64];
  __shared__ unsigned short Bs[128 * 64];
  const int tid  = threadIdx.x;
  const int lane = tid & 63;
  const int wid  = tid >> 6;
  const int wr   = wid >> 1, wc = wid & 1;
  const int l15  = lane & 15, l4 = lane >> 4;
  const int bm   = blockIdx.x, bn = blockIdx.y;

  f32x4 acc[4][4] = {};

  const unsigned short* qbase = Qb + (long)bm * 128 * ND;
  const unsigned short* cbase = Cb + (long)bn * 128 * ND;

  for (int k0 = 0; k0 < ND; k0 += 64) {
    __syncthreads();   // previous compute done before overwrite
    #pragma unroll
    for (int j = 0; j < 4; ++j) {
      const int e = j * 256 + tid;
      const int r = e >> 3;
      const int c = (e & 7) * 8;
      gload_lds16(qbase + (long)r * ND + k0 + c, &As[e * 8]);
      gload_lds16(cbase + (long)r * ND + k0 + c, &Bs[e * 8]);
    }
    __syncthreads();   // drains vmcnt -> tiles ready
    #pragma unroll
    for (int kk = 0; kk < 2; ++kk) {
      bf16x8 a[4], b[4];
      const int ka = kk * 32 + l4 * 8;
      #pragma unroll
      for (int i = 0; i < 4; ++i) a[i] = *(const bf16x8*)&As[(wr * 64 + i * 16 + l15) * 64 + ka];
      #pragma unroll
      for (int j = 0; j < 4; ++j) b[j] = *(const bf16x8*)&Bs[(wc * 64 + j * 16 + l15) * 64 + ka];
      #pragma unroll
      for (int i = 0; i < 4; ++i)
        #pragma unroll
        for (int j = 0; j < 4; ++j)
          acc[i][j] = __builtin_amdgcn_mfma_f32_16x16x32_bf16(a[i], b[j], acc[i][j], 0, 0, 0);
    }
  }

  // epilogue: per lane 16 rows x 4 cols; C/D map: col = lane&15, row = (lane>>4)*4 + reg
  const int rbase = bm * 128 + wr * 64;
  const int cb0   = bn * 128 + wc * 64 + l15;
  #pragma unroll
  for (int i = 0; i < 4; ++i) {
    #pragma unroll
    for (int r = 0; r < 4; ++r) {
      const int grow = rbase + i * 16 + l4 * 4 + r;
      const float c   = curv[grow];
      const float xs  = xsq[grow];
      const float sc  = __builtin_amdgcn_sqrtf(c + EPSF);
      const float inv = __builtin_amdgcn_rcpf(sc + EPSF);   // 1/(sqrt_c+eps)
      const float mxn = inv - EPSF;                          // max_norm
      const float Bc  = fmaf(-c, xs, 1.f);
      const float c2xs = c * c * xs;
      const float n2c  = -2.f * c;
      float s = 0.f;
      #pragma unroll
      for (int j = 0; j < 4; ++j) {
        const float xy  = acc[i][j][r];
        const int gcol  = cb0 + j * 16;
        const float ys  = ysq[gcol];
        const float A   = fmaf(c, fmaf(-2.f, xy, ys), 1.f);
        const float Axy = A * xy;
        const float nsq = fmaf(A * xs, A, Bc * fmaf(Bc, ys, -2.f * Axy));
        const float den = fmaf(c2xs, ys, fmaf(n2c, xy, 1.f)) + EPSF;
        float dn = __builtin_amdgcn_sqrtf(fmaxf(nsq, 0.f)) * __builtin_amdgcn_rcpf(den);
        dn = fminf(fmaxf(dn, EPSF), mxn);
        const float t   = fminf(sc * dn, 1.f - EPSF);
        const float at2 = __logf((1.f + t) * __builtin_amdgcn_rcpf(1.f - t)); // 2*atanh(t)
        const float dist = inv * at2;     // (2/(sqrt_c+eps)) * atanh
        const bool valid = gcol < NCAND;
        const float bi = valid ? bias[gcol] : 0.f;
        const float e  = valid ? __expf(bi - dist) : 0.f;
        s += e;
      }
      // reduce over the 16 lanes sharing this row (bits 0..3 of lane)
      s += __shfl_xor(s, 1, 64);
      s += __shfl_xor(s, 2, 64);
      s += __shfl_xor(s, 4, 64);
      s += __shfl_xor(s, 8, 64);
      if (l15 == 0) partials[(long)grow * NCHUNK + (bn * 2 + wc)] = s;
    }
  }
}

// ---------- per-row LSE + final mean (atomic) ----------
__global__ __launch_bounds__(128) void lse_final_kernel(
    const float* __restrict__ partials, const float* __restrict__ tgtl,
    float* __restrict__ out)
{
  const int b = blockIdx.x;
  const int tid = threadIdx.x;
  float s = 0.f;
  for (int i = tid; i < NCHUNK; i += 128) s += partials[(long)b * NCHUNK + i];
  #pragma unroll
  for (int m = 1; m < 64; m <<= 1) s += __shfl_xor(s, m, 64);
  __shared__ float red[2];
  if ((tid & 63) == 0) red[tid >> 6] = s;
  __syncthreads();
  if (tid == 0) {
    const float tot = red[0] + red[1];
    const float v = (logf(tot) - tgtl[b]) * (1.0f / (float)NB);
    atomicAdd(out, v);
  }
}

// ---------- launch ----------
extern "C" void kernel_launch(void* const* d_in, const int* in_sizes, int n_in,
                              void* d_out, int out_size, void* d_ws, size_t ws_size,
                              hipStream_t stream) {
  const float* q    = (const float*)d_in[0];
  const float* cand = (const float*)d_in[1];
  const float* bias = (const float*)d_in[2];
  const float* curv = (const float*)d_in[3];
  const int*   tgt  = (const int*)d_in[4];
  float* out = (float*)d_out;

  char* ws = (char*)d_ws;
  // layout (bytes):
  unsigned short* cb = (unsigned short*)(ws);                 // NPAD*ND*2   = 41,025,536
  unsigned short* qb = (unsigned short*)(ws + 41025536);      // NB*ND*2    =  1,048,576
  float* ysq         = (float*)(ws + 42074112);               // NPAD*4     =    160,256
  float* xsq         = (float*)(ws + 42234368);               // NB*4       =      4,096
  float* partials    = (float*)(ws + 42238464);               // NB*NCHUNK*4=  2,564,096
  float* tgtl        = (float*)(ws + 44802560);               // NB*4       =      4,096

  hipMemsetAsync(out, 0, sizeof(float), stream);
  prep_kernel<<<NPAD / 4, 256, 0, stream>>>(cand, cb, ysq, NCAND, NPAD);
  prep_kernel<<<NB / 4,  256, 0, stream>>>(q, qb, xsq, NB, NB);
  tgt_kernel<<<NB, 64, 0, stream>>>(q, cand, bias, curv, tgt, tgtl);
  gemm_epi_kernel<<<dim3(8, 313), 256, 0, stream>>>(qb, cb, xsq, ysq, curv, bias, partials);
  lse_final_kernel<<<NB, 128, 0, stream>>>(partials, tgtl, out);
}

// Round 2
// 244.864 us; speedup vs baseline: 1.2410x; 1.2410x over previous
//
#include <hip/hip_runtime.h>
#include <math.h>

#define EPSF 1e-6f
#define NB    1024
#define ND    512
#define NCAND 40000
#define NPAD  40064          // 313 * 128
#define NCHUNK 626           // NPAD / 64 : one partial per (row, 64-col chunk)
#define LOG2E 1.44269504088896340736f

typedef __attribute__((ext_vector_type(8))) short          bf16x8;
typedef __attribute__((ext_vector_type(8))) unsigned short ushort8;
typedef __attribute__((ext_vector_type(4))) float          f32x4;

// ---------- helpers ----------
__device__ __forceinline__ unsigned short f2bf(float f) {
  union { float f; unsigned int u; } v; v.f = f;
  unsigned int u = v.u;
  return (unsigned short)((u + 0x7FFFu + ((u >> 16) & 1u)) >> 16);  // RNE
}

__device__ __forceinline__ void gload_lds16(const void* g, void* l) {
  __builtin_amdgcn_global_load_lds(
      (const __attribute__((address_space(1))) void*)g,
      (__attribute__((address_space(3))) void*)l, 16, 0, 0);
}

// ---------- prep: fp32 -> bf16 rows + sum-of-squares (exact fp32) ----------
// one wave per row; 4 rows per 256-thread block.
// Optional extras: b2 (bias*log2e, padded with -inf), rcst (per-row float4).
__global__ __launch_bounds__(256) void prep_kernel(
    const float* __restrict__ src, unsigned short* __restrict__ dst,
    float* __restrict__ sq, int nfull, int npad,
    const float* __restrict__ curv, float4* __restrict__ rcst,
    const float* __restrict__ bias, float* __restrict__ b2)
{
  const int wid = threadIdx.x >> 6, lane = threadIdx.x & 63;
  if (b2) {
    const int g = blockIdx.x * 256 + threadIdx.x;
    if (g < NPAD) b2[g] = (g < NCAND) ? bias[g] * LOG2E : -INFINITY;
  }
  const long row = (long)blockIdx.x * 4 + wid;
  if (row >= npad) return;
  float vals[8];
  if (row < nfull) {
    const float4* s = (const float4*)(src + row * ND + lane * 8);
    float4 a = s[0], b = s[1];
    vals[0]=a.x; vals[1]=a.y; vals[2]=a.z; vals[3]=a.w;
    vals[4]=b.x; vals[5]=b.y; vals[6]=b.z; vals[7]=b.w;
  } else {
    #pragma unroll
    for (int i = 0; i < 8; ++i) vals[i] = 0.f;
  }
  float ss = 0.f;
  ushort8 o;
  #pragma unroll
  for (int i = 0; i < 8; ++i) { ss = fmaf(vals[i], vals[i], ss); o[i] = f2bf(vals[i]); }
  *(ushort8*)(dst + row * ND + lane * 8) = o;
  #pragma unroll
  for (int m = 1; m < 64; m <<= 1) ss += __shfl_xor(ss, m, 64);
  if (lane == 0) {
    sq[row] = ss;
    if (rcst && row < nfull) {
      const float c   = curv[row];
      const float scv = sqrtf(c + EPSF);
      const float inv = 1.f / (scv + EPSF);
      rcst[row] = make_float4(c, ss, scv, inv);
    }
  }
}

// ---------- exact fp32 target logit, one wave per row ----------
__global__ __launch_bounds__(64) void tgt_kernel(
    const float* __restrict__ q, const float* __restrict__ cand,
    const float* __restrict__ bias, const float* __restrict__ curv,
    const int* __restrict__ target, float* __restrict__ tgtl)
{
  const int b = blockIdx.x, lane = threadIdx.x;
  const int t = target[b];
  const float4* qp = (const float4*)(q + (long)b * ND + lane * 8);
  const float4* cp = (const float4*)(cand + (long)t * ND + lane * 8);
  float4 a0 = qp[0], a1 = qp[1], c0 = cp[0], c1 = cp[1];
  float qa[8] = {a0.x,a0.y,a0.z,a0.w,a1.x,a1.y,a1.z,a1.w};
  float ca[8] = {c0.x,c0.y,c0.z,c0.w,c1.x,c1.y,c1.z,c1.w};
  float xy = 0.f, xs = 0.f, ys = 0.f;
  #pragma unroll
  for (int i = 0; i < 8; ++i) {
    xy = fmaf(qa[i], ca[i], xy);
    xs = fmaf(qa[i], qa[i], xs);
    ys = fmaf(ca[i], ca[i], ys);
  }
  #pragma unroll
  for (int m = 1; m < 64; m <<= 1) {
    xy += __shfl_xor(xy, m, 64);
    xs += __shfl_xor(xs, m, 64);
    ys += __shfl_xor(ys, m, 64);
  }
  if (lane == 0) {
    float c  = curv[b];
    float sc = sqrtf(c + EPSF);
    float A  = 1.f - 2.f * c * xy + c * ys;
    float Bc = 1.f - c * xs;
    float nsq = A * A * xs - 2.f * A * Bc * xy + Bc * Bc * ys;
    float den = 1.f - 2.f * c * xy + c * c * xs * ys;
    float dn  = sqrtf(fmaxf(nsq, 0.f)) / (den + EPSF);
    dn = fminf(fmaxf(dn, EPSF), 1.f / (sc + EPSF) - EPSF);
    float tt  = fminf(sc * dn, 1.f - EPSF);
    float dist = 2.f / (sc + EPSF) * atanhf(tt);
    tgtl[b] = bias[t] - dist;
  }
}

// ---------- fused bf16 GEMM + hyperbolic epilogue + partial expsum ----------
// 128x128 tile, BK=64, 256 threads (4 waves in 2x2), 4x4 frags of 16x16x32.
// LDS tiles XOR-swizzled (T2, both-sides per rule #21): data(r,c) lives at
// byte r*128 + ((c*2) ^ ((r&7)<<4)); staged via pre-swizzled GLOBAL source.
__global__ __launch_bounds__(256) void gemm_epi_kernel(
    const unsigned short* __restrict__ Qb,   // [NB][ND] bf16
    const unsigned short* __restrict__ Cb,   // [NPAD][ND] bf16
    const float4* __restrict__ rcst,         // [NB] (c, xs, sc, inv)
    const float* __restrict__ ysq,           // [NPAD]
    const float* __restrict__ b2,            // [NPAD] bias*log2e, pad=-inf
    float* __restrict__ partials)            // [NB][NCHUNK]
{
  __shared__ unsigned short As[128 * 64];
  __shared__ unsigned short Bs[128 * 64];
  const int tid  = threadIdx.x;
  const int lane = tid & 63;
  const int wid  = tid >> 6;
  const int wr   = wid >> 1, wc = wid & 1;
  const int l15  = lane & 15, l4 = lane >> 4;

  // XCD-aware remap (T1): each XCD owns a contiguous bn range; the 8 bm's of
  // one bn run back-to-back on the same XCD (B-tile stays L2-hot).
  const int h  = blockIdx.x;            // 2504 = 8*313
  const int w  = (h & 7) * 313 + (h >> 3);
  const int bm = w & 7, bn = w >> 3;

  f32x4 acc[4][4] = {};

  const unsigned short* qbase = Qb + (long)bm * 128 * ND;
  const unsigned short* cbase = Cb + (long)bn * 128 * ND;

  for (int k0 = 0; k0 < ND; k0 += 64) {
    __syncthreads();   // previous compute done before overwrite
    #pragma unroll
    for (int j = 0; j < 4; ++j) {
      const int e = j * 256 + tid;
      const int r = e >> 3;
      const int c = ((e & 7) ^ (r & 7)) * 8;   // pre-swizzled source column
      gload_lds16(qbase + (long)r * ND + k0 + c, &As[e * 8]);
      gload_lds16(cbase + (long)r * ND + k0 + c, &Bs[e * 8]);
    }
    __syncthreads();   // drains vmcnt -> tiles ready
    #pragma unroll
    for (int kk = 0; kk < 2; ++kk) {
      bf16x8 a[4], b[4];
      const int kb = (kk * 32 + l4 * 8) * 2;   // byte offset of K-slice
      #pragma unroll
      for (int i = 0; i < 4; ++i) {
        const int row = wr * 64 + i * 16 + l15;
        a[i] = *(const bf16x8*)((const char*)As + row * 128 + (kb ^ ((row & 7) << 4)));
      }
      #pragma unroll
      for (int j = 0; j < 4; ++j) {
        const int row = wc * 64 + j * 16 + l15;
        b[j] = *(const bf16x8*)((const char*)Bs + row * 128 + (kb ^ ((row & 7) << 4)));
      }
      #pragma unroll
      for (int i = 0; i < 4; ++i)
        #pragma unroll
        for (int j = 0; j < 4; ++j)
          acc[i][j] = __builtin_amdgcn_mfma_f32_16x16x32_bf16(a[i], b[j], acc[i][j], 0, 0, 0);
    }
  }

  // epilogue: C/D map col=lane&15, row=(lane>>4)*4+reg.
  // e = exp(bias - dist) = exp2(b2 - inv*log2((den+g)/(den-g))), g = sc*sqrt(nsq).
  // Clamps (dn in [eps, max_norm], t <= 1-eps) are provably non-binding here.
  const int rbase = bm * 128 + wr * 64;
  const int cb0   = bn * 128 + wc * 64 + l15;
  #pragma unroll
  for (int i = 0; i < 4; ++i) {
    #pragma unroll
    for (int r = 0; r < 4; ++r) {
      const int grow = rbase + i * 16 + l4 * 4 + r;
      const float4 rc = rcst[grow];
      const float cc = rc.x, xs = rc.y, sc = rc.z, inv = rc.w;
      const float Bc   = fmaf(-cc, xs, 1.f);
      const float n2c  = -2.f * cc;
      const float c2xs = cc * cc * xs;
      float s = 0.f;
      #pragma unroll
      for (int j = 0; j < 4; ++j) {
        const float xy  = acc[i][j][r];
        const int gcol  = cb0 + j * 16;
        const float ys  = ysq[gcol];
        const float b2v = b2[gcol];
        const float A   = fmaf(cc, fmaf(-2.f, xy, ys), 1.f);
        const float Axy = A * xy;
        const float nsq = fmaf(A * xs, A, fmaf(Bc, fmaf(Bc, ys, -2.f * Axy), 0.f));
        const float den = fmaf(c2xs, ys, fmaf(n2c, xy, 1.f + EPSF));
        const float g   = sc * __builtin_amdgcn_sqrtf(fmaxf(nsq, 0.f));
        const float rr  = (den + g) * __builtin_amdgcn_rcpf(den - g);
        const float lg  = __builtin_amdgcn_logf(rr);          // log2
        s += __builtin_amdgcn_exp2f(fmaf(-inv, lg, b2v));     // exp2
      }
      // reduce over the 16 lanes sharing this row
      s += __shfl_xor(s, 1, 64);
      s += __shfl_xor(s, 2, 64);
      s += __shfl_xor(s, 4, 64);
      s += __shfl_xor(s, 8, 64);
      if (l15 == 0) partials[(long)grow * NCHUNK + (bn * 2 + wc)] = s;
    }
  }
}

// ---------- per-row LSE + final mean (atomic) ----------
__global__ __launch_bounds__(128) void lse_final_kernel(
    const float* __restrict__ partials, const float* __restrict__ tgtl,
    float* __restrict__ out)
{
  const int b = blockIdx.x;
  const int tid = threadIdx.x;
  float s = 0.f;
  for (int i = tid; i < NCHUNK; i += 128) s += partials[(long)b * NCHUNK + i];
  #pragma unroll
  for (int m = 1; m < 64; m <<= 1) s += __shfl_xor(s, m, 64);
  __shared__ float red[2];
  if ((tid & 63) == 0) red[tid >> 6] = s;
  __syncthreads();
  if (tid == 0) {
    const float tot = red[0] + red[1];
    const float v = (logf(tot) - tgtl[b]) * (1.0f / (float)NB);
    atomicAdd(out, v);
  }
}

// ---------- launch ----------
extern "C" void kernel_launch(void* const* d_in, const int* in_sizes, int n_in,
                              void* d_out, int out_size, void* d_ws, size_t ws_size,
                              hipStream_t stream) {
  const float* q    = (const float*)d_in[0];
  const float* cand = (const float*)d_in[1];
  const float* bias = (const float*)d_in[2];
  const float* curv = (const float*)d_in[3];
  const int*   tgt  = (const int*)d_in[4];
  float* out = (float*)d_out;

  char* ws = (char*)d_ws;
  // layout (bytes):
  unsigned short* cb = (unsigned short*)(ws);                 // 41,025,536
  unsigned short* qb = (unsigned short*)(ws + 41025536);      //  1,048,576
  float* ysq         = (float*)(ws + 42074112);               //    160,256
  float* xsq         = (float*)(ws + 42234368);               //      4,096
  float* partials    = (float*)(ws + 42238464);               //  2,564,096
  float* tgtl        = (float*)(ws + 44802560);               //      4,096
  float* b2          = (float*)(ws + 44806656);               //    160,256
  float4* rcst       = (float4*)(ws + 44966912);              //     16,384 -> 44,983,296 total

  hipMemsetAsync(out, 0, sizeof(float), stream);
  prep_kernel<<<NPAD / 4, 256, 0, stream>>>(cand, cb, ysq, NCAND, NPAD,
                                            nullptr, nullptr, bias, b2);
  prep_kernel<<<NB / 4,  256, 0, stream>>>(q, qb, xsq, NB, NB,
                                           curv, rcst, nullptr, nullptr);
  tgt_kernel<<<NB, 64, 0, stream>>>(q, cand, bias, curv, tgt, tgtl);
  gemm_epi_kernel<<<2504, 256, 0, stream>>>(qb, cb, rcst, ysq, b2, partials);
  lse_final_kernel<<<NB, 128, 0, stream>>>(partials, tgtl, out);
}

// Round 3
// 213.108 us; speedup vs baseline: 1.4259x; 1.1490x over previous
//
#include <hip/hip_runtime.h>
#include <math.h>

#define EPSF 1e-6f
#define NB    1024
#define ND    512
#define NCAND 40000
#define NPAD  40064          // 313 * 128
#define NCHUNK 626           // NPAD / 64 : one partial per (row, 64-col chunk)
#define LOG2E 1.44269504088896340736f

typedef __attribute__((ext_vector_type(8))) short          bf16x8;
typedef __attribute__((ext_vector_type(8))) unsigned short ushort8;
typedef __attribute__((ext_vector_type(4))) float          f32x4;

// ---------- helpers ----------
__device__ __forceinline__ unsigned short f2bf(float f) {
  union { float f; unsigned int u; } v; v.f = f;
  unsigned int u = v.u;
  return (unsigned short)((u + 0x7FFFu + ((u >> 16) & 1u)) >> 16);  // RNE
}

__device__ __forceinline__ void gload_lds16(const void* g, void* l) {
  __builtin_amdgcn_global_load_lds(
      (const __attribute__((address_space(1))) void*)g,
      (__attribute__((address_space(3))) void*)l, 16, 0, 0);
}

// ---------- fused prep: one kernel does everything pre-GEMM ----------
// grid = NPAD/4 blocks x 256. All blocks: convert 4 candidate rows -> bf16 +
// ysq. Blocks < 256 additionally: convert 4 query rows -> bf16 + rcst,
// fill b2 (bias*log2e, pad=-inf), compute 4 exact target logits, zero out.
__global__ __launch_bounds__(256) void prep_all_kernel(
    const float* __restrict__ q, const float* __restrict__ cand,
    const float* __restrict__ bias, const float* __restrict__ curv,
    const int* __restrict__ target,
    unsigned short* __restrict__ qb, unsigned short* __restrict__ cb,
    float* __restrict__ ysq, float4* __restrict__ rcst,
    float* __restrict__ b2, float* __restrict__ tgtl, float* __restrict__ out)
{
  const int blk = blockIdx.x;
  const int tid = threadIdx.x, wid = tid >> 6, lane = tid & 63;

  // ---- candidate rows (all blocks) ----
  {
    const long row = (long)blk * 4 + wid;          // < NPAD by grid size
    float vals[8];
    if (row < NCAND) {
      const float4* s = (const float4*)(cand + row * ND + lane * 8);
      float4 a = s[0], b = s[1];
      vals[0]=a.x; vals[1]=a.y; vals[2]=a.z; vals[3]=a.w;
      vals[4]=b.x; vals[5]=b.y; vals[6]=b.z; vals[7]=b.w;
    } else {
      #pragma unroll
      for (int i = 0; i < 8; ++i) vals[i] = 0.f;
    }
    float ss = 0.f; ushort8 o;
    #pragma unroll
    for (int i = 0; i < 8; ++i) { ss = fmaf(vals[i], vals[i], ss); o[i] = f2bf(vals[i]); }
    *(ushort8*)(cb + row * ND + lane * 8) = o;
    #pragma unroll
    for (int m = 1; m < 64; m <<= 1) ss += __shfl_xor(ss, m, 64);
    if (lane == 0) ysq[row] = ss;
  }

  if (blk >= 256) return;

  // ---- b2 fill (256 blocks x 256 threads = 65536 >= NPAD) ----
  {
    const int g = blk * 256 + tid;
    if (g < NPAD) b2[g] = (g < NCAND) ? bias[g] * LOG2E : -INFINITY;
  }

  // ---- query rows ----
  {
    const long row = (long)blk * 4 + wid;          // < 1024
    const float4* s = (const float4*)(q + row * ND + lane * 8);
    float4 a = s[0], b = s[1];
    float vals[8] = {a.x,a.y,a.z,a.w,b.x,b.y,b.z,b.w};
    float ss = 0.f; ushort8 o;
    #pragma unroll
    for (int i = 0; i < 8; ++i) { ss = fmaf(vals[i], vals[i], ss); o[i] = f2bf(vals[i]); }
    *(ushort8*)(qb + row * ND + lane * 8) = o;
    #pragma unroll
    for (int m = 1; m < 64; m <<= 1) ss += __shfl_xor(ss, m, 64);
    if (lane == 0) {
      const float c   = curv[row];
      const float scv = sqrtf(c + EPSF);
      const float inv = 1.f / (scv + EPSF);
      // (negc, Bc, inv, 2*c^2*xs)
      rcst[row] = make_float4(-c, fmaf(-c, ss, 1.f), inv, 2.f * c * c * ss);
    }
  }

  // ---- exact fp32 target logit (wave per row) ----
  {
    const int b = blk * 4 + wid;                   // < 1024
    const int t = target[b];
    const float4* qp = (const float4*)(q + (long)b * ND + lane * 8);
    const float4* cp = (const float4*)(cand + (long)t * ND + lane * 8);
    float4 a0 = qp[0], a1 = qp[1], c0 = cp[0], c1 = cp[1];
    float qa[8] = {a0.x,a0.y,a0.z,a0.w,a1.x,a1.y,a1.z,a1.w};
    float ca[8] = {c0.x,c0.y,c0.z,c0.w,c1.x,c1.y,c1.z,c1.w};
    float xy = 0.f, xs = 0.f, ys = 0.f;
    #pragma unroll
    for (int i = 0; i < 8; ++i) {
      xy = fmaf(qa[i], ca[i], xy);
      xs = fmaf(qa[i], qa[i], xs);
      ys = fmaf(ca[i], ca[i], ys);
    }
    #pragma unroll
    for (int m = 1; m < 64; m <<= 1) {
      xy += __shfl_xor(xy, m, 64);
      xs += __shfl_xor(xs, m, 64);
      ys += __shfl_xor(ys, m, 64);
    }
    if (lane == 0) {
      float c  = curv[b];
      float sc = sqrtf(c + EPSF);
      float A  = 1.f - 2.f * c * xy + c * ys;
      float Bc = 1.f - c * xs;
      float nsq = A * A * xs - 2.f * A * Bc * xy + Bc * Bc * ys;
      float den = 1.f - 2.f * c * xy + c * c * xs * ys;
      float dn  = sqrtf(fmaxf(nsq, 0.f)) / (den + EPSF);
      dn = fminf(fmaxf(dn, EPSF), 1.f / (sc + EPSF) - EPSF);
      float tt  = fminf(sc * dn, 1.f - EPSF);
      float dist = 2.f / (sc + EPSF) * atanhf(tt);
      tgtl[b] = bias[t] - dist;
    }
  }

  // ---- zero output accumulator (stream order guarantees before lse) ----
  if (blk == 0 && tid == 0) out[0] = 0.f;
}

// ---------- fused bf16 GEMM + acosh epilogue + partial expsum ----------
// 128x128 tile, BK=64, 256 threads (4 waves in 2x2), 4x4 frags of 16x16x32.
// LDS tiles XOR-swizzled (T2, both-sides per rule #21).
// Epilogue via Mobius identity: den^2 - c*num_sq = Bc*By*den  =>
//   cosh(2 atanh z) = 2*den/(Bc*By) - 1 = w,  dist = inv*ln(w + sqrt(w^2-1)).
__global__ __launch_bounds__(256, 3) void gemm_epi_kernel(
    const unsigned short* __restrict__ Qb,   // [NB][ND] bf16
    const unsigned short* __restrict__ Cb,   // [NPAD][ND] bf16
    const float4* __restrict__ rcst,         // [NB] (negc, Bc, inv, 2c^2xs)
    const float* __restrict__ ysq,           // [NPAD]
    const float* __restrict__ b2,            // [NPAD] bias*log2e, pad=-inf
    float* __restrict__ partials)            // [NB][NCHUNK]
{
  __shared__ unsigned short As[128 * 64];
  __shared__ unsigned short Bs[128 * 64];
  const int tid  = threadIdx.x;
  const int lane = tid & 63;
  const int wid  = tid >> 6;
  const int wr   = wid >> 1, wc = wid & 1;
  const int l15  = lane & 15, l4 = lane >> 4;

  // XCD-aware remap (T1)
  const int h  = blockIdx.x;            // 2504 = 8*313
  const int w  = (h & 7) * 313 + (h >> 3);
  const int bm = w & 7, bn = w >> 3;

  f32x4 acc[4][4] = {};

  const unsigned short* qbase = Qb + (long)bm * 128 * ND;
  const unsigned short* cbase = Cb + (long)bn * 128 * ND;

  for (int k0 = 0; k0 < ND; k0 += 64) {
    __syncthreads();
    #pragma unroll
    for (int j = 0; j < 4; ++j) {
      const int e = j * 256 + tid;
      const int r = e >> 3;
      const int c = ((e & 7) ^ (r & 7)) * 8;   // pre-swizzled source column
      gload_lds16(qbase + (long)r * ND + k0 + c, &As[e * 8]);
      gload_lds16(cbase + (long)r * ND + k0 + c, &Bs[e * 8]);
    }
    __syncthreads();
    #pragma unroll
    for (int kk = 0; kk < 2; ++kk) {
      bf16x8 a[4], b[4];
      const int kb = (kk * 32 + l4 * 8) * 2;   // byte offset of K-slice
      #pragma unroll
      for (int i = 0; i < 4; ++i) {
        const int row = wr * 64 + i * 16 + l15;
        a[i] = *(const bf16x8*)((const char*)As + row * 128 + (kb ^ ((row & 7) << 4)));
      }
      #pragma unroll
      for (int j = 0; j < 4; ++j) {
        const int row = wc * 64 + j * 16 + l15;
        b[j] = *(const bf16x8*)((const char*)Bs + row * 128 + (kb ^ ((row & 7) << 4)));
      }
      #pragma unroll
      for (int i = 0; i < 4; ++i)
        #pragma unroll
        for (int j = 0; j < 4; ++j)
          acc[i][j] = __builtin_amdgcn_mfma_f32_16x16x32_bf16(a[i], b[j], acc[i][j], 0, 0, 0);
    }
  }

  // ---- epilogue ----
  const int rbase = bm * 128 + wr * 64;
  const int cb0   = bn * 128 + wc * 64 + l15;
  // hoist the only 4 distinct columns this lane touches
  float ysv[4], bv[4];
  #pragma unroll
  for (int j = 0; j < 4; ++j) { ysv[j] = ysq[cb0 + j * 16]; bv[j] = b2[cb0 + j * 16]; }

  #pragma unroll
  for (int i = 0; i < 4; ++i) {
    #pragma unroll
    for (int r = 0; r < 4; ++r) {
      const int grow = rbase + i * 16 + l4 * 4 + r;
      const float4 rc = rcst[grow];
      const float negc = rc.x, Bc = rc.y, inv = rc.z, c2xs2 = rc.w;
      const float n4c = 4.f * negc;               // -4c
      float s = 0.f;
      #pragma unroll
      for (int j = 0; j < 4; ++j) {
        const float xy   = acc[i][j][r];
        const float By   = fmaf(negc, ysv[j], 1.f);
        const float P    = Bc * By;
        const float den2 = fmaf(c2xs2, ysv[j], fmaf(n4c, xy, 2.f));   // 2*den
        const float wv   = fmaf(den2, __builtin_amdgcn_rcpf(P), -1.f);
        const float t2   = fmaxf(fmaf(wv, wv, -1.f), 0.f);
        const float W    = wv + __builtin_amdgcn_sqrtf(t2);
        const float lg   = __builtin_amdgcn_logf(W);                  // log2
        s += __builtin_amdgcn_exp2f(fmaf(-inv, lg, bv[j]));
      }
      s += __shfl_xor(s, 1, 64);
      s += __shfl_xor(s, 2, 64);
      s += __shfl_xor(s, 4, 64);
      s += __shfl_xor(s, 8, 64);
      if (l15 == 0) partials[(long)grow * NCHUNK + (bn * 2 + wc)] = s;
    }
  }
}

// ---------- per-row LSE + final mean (atomic) ----------
__global__ __launch_bounds__(128) void lse_final_kernel(
    const float* __restrict__ partials, const float* __restrict__ tgtl,
    float* __restrict__ out)
{
  const int b = blockIdx.x;
  const int tid = threadIdx.x;
  float s = 0.f;
  for (int i = tid; i < NCHUNK; i += 128) s += partials[(long)b * NCHUNK + i];
  #pragma unroll
  for (int m = 1; m < 64; m <<= 1) s += __shfl_xor(s, m, 64);
  __shared__ float red[2];
  if ((tid & 63) == 0) red[tid >> 6] = s;
  __syncthreads();
  if (tid == 0) {
    const float tot = red[0] + red[1];
    const float v = (logf(tot) - tgtl[b]) * (1.0f / (float)NB);
    atomicAdd(out, v);
  }
}

// ---------- launch ----------
extern "C" void kernel_launch(void* const* d_in, const int* in_sizes, int n_in,
                              void* d_out, int out_size, void* d_ws, size_t ws_size,
                              hipStream_t stream) {
  const float* q    = (const float*)d_in[0];
  const float* cand = (const float*)d_in[1];
  const float* bias = (const float*)d_in[2];
  const float* curv = (const float*)d_in[3];
  const int*   tgt  = (const int*)d_in[4];
  float* out = (float*)d_out;

  char* ws = (char*)d_ws;
  unsigned short* cb = (unsigned short*)(ws);                 // 41,025,536
  unsigned short* qb = (unsigned short*)(ws + 41025536);      //  1,048,576
  float*  ysq        = (float*) (ws + 42074112);              //    160,256
  float*  b2         = (float*) (ws + 42234368);              //    160,256
  float4* rcst       = (float4*)(ws + 42394624);              //     16,384
  float*  tgtl       = (float*) (ws + 42411008);              //      4,096
  float*  partials   = (float*) (ws + 42415104);              //  2,564,096 -> end 44,979,200

  prep_all_kernel<<<NPAD / 4, 256, 0, stream>>>(q, cand, bias, curv, tgt,
                                                qb, cb, ysq, rcst, b2, tgtl, out);
  gemm_epi_kernel<<<2504, 256, 0, stream>>>(qb, cb, rcst, ysq, b2, partials);
  lse_final_kernel<<<NB, 128, 0, stream>>>(partials, tgtl, out);
}

// Round 5
// 190.980 us; speedup vs baseline: 1.5911x; 1.1159x over previous
//
#include <hip/hip_runtime.h>
#include <math.h>

#define EPSF 1e-6f
#define NB    1024
#define ND    512
#define NCAND 40000
#define NPAD  40064          // 313 * 128
#define NCHUNK 626           // NPAD / 64 : one partial per (row, 64-col chunk)
#define LOG2E 1.44269504088896340736f

typedef __attribute__((ext_vector_type(8))) short          bf16x8;
typedef __attribute__((ext_vector_type(8))) unsigned short ushort8;
typedef __attribute__((ext_vector_type(4))) float          f32x4;

// ---------- helpers ----------
__device__ __forceinline__ unsigned short f2bf(float f) {
  union { float f; unsigned int u; } v; v.f = f;
  unsigned int u = v.u;
  return (unsigned short)((u + 0x7FFFu + ((u >> 16) & 1u)) >> 16);  // RNE
}

__device__ __forceinline__ void gload_lds16(const void* g, void* l) {
  __builtin_amdgcn_global_load_lds(
      (const __attribute__((address_space(1))) void*)g,
      (__attribute__((address_space(3))) void*)l, 16, 0, 0);
}

// ---------- fused prep: one kernel does everything pre-GEMM ----------
__global__ __launch_bounds__(256) void prep_all_kernel(
    const float* __restrict__ q, const float* __restrict__ cand,
    const float* __restrict__ bias, const float* __restrict__ curv,
    const int* __restrict__ target,
    unsigned short* __restrict__ qb, unsigned short* __restrict__ cb,
    float* __restrict__ ysq, float4* __restrict__ rcst,
    float* __restrict__ b2, float* __restrict__ tgtl)
{
  const int blk = blockIdx.x;
  const int tid = threadIdx.x, wid = tid >> 6, lane = tid & 63;

  // ---- candidate rows (all blocks) ----
  {
    const long row = (long)blk * 4 + wid;          // < NPAD by grid size
    float vals[8];
    if (row < NCAND) {
      const float4* s = (const float4*)(cand + row * ND + lane * 8);
      float4 a = s[0], b = s[1];
      vals[0]=a.x; vals[1]=a.y; vals[2]=a.z; vals[3]=a.w;
      vals[4]=b.x; vals[5]=b.y; vals[6]=b.z; vals[7]=b.w;
    } else {
      #pragma unroll
      for (int i = 0; i < 8; ++i) vals[i] = 0.f;
    }
    float ss = 0.f; ushort8 o;
    #pragma unroll
    for (int i = 0; i < 8; ++i) { ss = fmaf(vals[i], vals[i], ss); o[i] = f2bf(vals[i]); }
    *(ushort8*)(cb + row * ND + lane * 8) = o;
    #pragma unroll
    for (int m = 1; m < 64; m <<= 1) ss += __shfl_xor(ss, m, 64);
    if (lane == 0) ysq[row] = ss;
  }

  if (blk >= 256) return;

  // ---- b2 fill ----
  {
    const int g = blk * 256 + tid;
    if (g < NPAD) b2[g] = (g < NCAND) ? bias[g] * LOG2E : -INFINITY;
  }

  // ---- query rows ----
  {
    const long row = (long)blk * 4 + wid;          // < 1024
    const float4* s = (const float4*)(q + row * ND + lane * 8);
    float4 a = s[0], b = s[1];
    float vals[8] = {a.x,a.y,a.z,a.w,b.x,b.y,b.z,b.w};
    float ss = 0.f; ushort8 o;
    #pragma unroll
    for (int i = 0; i < 8; ++i) { ss = fmaf(vals[i], vals[i], ss); o[i] = f2bf(vals[i]); }
    *(ushort8*)(qb + row * ND + lane * 8) = o;
    #pragma unroll
    for (int m = 1; m < 64; m <<= 1) ss += __shfl_xor(ss, m, 64);
    if (lane == 0) {
      const float c   = curv[row];
      const float scv = sqrtf(c + EPSF);
      const float inv = 1.f / (scv + EPSF);
      rcst[row] = make_float4(-c, fmaf(-c, ss, 1.f), inv, 2.f * c * c * ss);
    }
  }

  // ---- exact fp32 target logit (wave per row) ----
  {
    const int b = blk * 4 + wid;                   // < 1024
    const int t = target[b];
    const float4* qp = (const float4*)(q + (long)b * ND + lane * 8);
    const float4* cp = (const float4*)(cand + (long)t * ND + lane * 8);
    float4 a0 = qp[0], a1 = qp[1], c0 = cp[0], c1 = cp[1];
    float qa[8] = {a0.x,a0.y,a0.z,a0.w,a1.x,a1.y,a1.z,a1.w};
    float ca[8] = {c0.x,c0.y,c0.z,c0.w,c1.x,c1.y,c1.z,c1.w};
    float xy = 0.f, xs = 0.f, ys = 0.f;
    #pragma unroll
    for (int i = 0; i < 8; ++i) {
      xy = fmaf(qa[i], ca[i], xy);
      xs = fmaf(qa[i], qa[i], xs);
      ys = fmaf(ca[i], ca[i], ys);
    }
    #pragma unroll
    for (int m = 1; m < 64; m <<= 1) {
      xy += __shfl_xor(xy, m, 64);
      xs += __shfl_xor(xs, m, 64);
      ys += __shfl_xor(ys, m, 64);
    }
    if (lane == 0) {
      float c  = curv[b];
      float sc = sqrtf(c + EPSF);
      float A  = 1.f - 2.f * c * xy + c * ys;
      float Bc = 1.f - c * xs;
      float nsq = A * A * xs - 2.f * A * Bc * xy + Bc * Bc * ys;
      float den = 1.f - 2.f * c * xy + c * c * xs * ys;
      float dn  = sqrtf(fmaxf(nsq, 0.f)) / (den + EPSF);
      dn = fminf(fmaxf(dn, EPSF), 1.f / (sc + EPSF) - EPSF);
      float tt  = fminf(sc * dn, 1.f - EPSF);
      float dist = 2.f / (sc + EPSF) * atanhf(tt);
      tgtl[b] = bias[t] - dist;
    }
  }
}

// ---------- fused bf16 GEMM + acosh epilogue + partial expsum ----------
// 128x128 tile, BK=64, 256 threads (4 waves in 2x2), 4x4 frags of 16x16x32.
// LDS XOR-swizzled (T2 both-sides); 4 blocks/CU for cross-block overlap.
__global__ __launch_bounds__(256, 4) void gemm_epi_kernel(
    const unsigned short* __restrict__ Qb,   // [NB][ND] bf16
    const unsigned short* __restrict__ Cb,   // [NPAD][ND] bf16
    const float4* __restrict__ rcst,         // [NB] (negc, Bc, inv, 2c^2xs)
    const float* __restrict__ ysq,           // [NPAD]
    const float* __restrict__ b2,            // [NPAD] bias*log2e, pad=-inf
    float* __restrict__ partials)            // [NB][NCHUNK]
{
  __shared__ unsigned short As[128 * 64];
  __shared__ unsigned short Bs[128 * 64];
  const int tid  = threadIdx.x;
  const int lane = tid & 63;
  const int wid  = tid >> 6;
  const int wr   = wid >> 1, wc = wid & 1;
  const int l15  = lane & 15, l4 = lane >> 4;

  // XCD-aware remap (T1)
  const int h  = blockIdx.x;            // 2504 = 8*313
  const int w  = (h & 7) * 313 + (h >> 3);
  const int bm = w & 7, bn = w >> 3;

  f32x4 acc[4][4] = {};

  const unsigned short* qbase = Qb + (long)bm * 128 * ND;
  const unsigned short* cbase = Cb + (long)bn * 128 * ND;

  for (int k0 = 0; k0 < ND; k0 += 64) {
    __syncthreads();
    #pragma unroll
    for (int j = 0; j < 4; ++j) {
      const int e = j * 256 + tid;
      const int r = e >> 3;
      const int c = ((e & 7) ^ (r & 7)) * 8;   // pre-swizzled source column
      gload_lds16(qbase + (long)r * ND + k0 + c, &As[e * 8]);
      gload_lds16(cbase + (long)r * ND + k0 + c, &Bs[e * 8]);
    }
    __syncthreads();
    #pragma unroll
    for (int kk = 0; kk < 2; ++kk) {
      bf16x8 a[4], b[4];
      const int kb = (kk * 32 + l4 * 8) * 2;   // byte offset of K-slice
      #pragma unroll
      for (int i = 0; i < 4; ++i) {
        const int row = wr * 64 + i * 16 + l15;
        a[i] = *(const bf16x8*)((const char*)As + row * 128 + (kb ^ ((row & 7) << 4)));
      }
      #pragma unroll
      for (int j = 0; j < 4; ++j) {
        const int row = wc * 64 + j * 16 + l15;
        b[j] = *(const bf16x8*)((const char*)Bs + row * 128 + (kb ^ ((row & 7) << 4)));
      }
      #pragma unroll
      for (int i = 0; i < 4; ++i)
        #pragma unroll
        for (int j = 0; j < 4; ++j)
          acc[i][j] = __builtin_amdgcn_mfma_f32_16x16x32_bf16(a[i], b[j], acc[i][j], 0, 0, 0);
    }
  }

  // ---- epilogue (acosh form) ----
  const int rbase = bm * 128 + wr * 64;
  const int cb0   = bn * 128 + wc * 64 + l15;
  float ysv[4], bv[4];
  #pragma unroll
  for (int j = 0; j < 4; ++j) { ysv[j] = ysq[cb0 + j * 16]; bv[j] = b2[cb0 + j * 16]; }

  #pragma unroll
  for (int i = 0; i < 4; ++i) {
    #pragma unroll
    for (int r = 0; r < 4; ++r) {
      const int grow = rbase + i * 16 + l4 * 4 + r;
      const float4 rc = rcst[grow];
      const float negc = rc.x, Bc = rc.y, inv = rc.z, c2xs2 = rc.w;
      const float n4c = 4.f * negc;               // -4c
      float s = 0.f;
      #pragma unroll
      for (int j = 0; j < 4; ++j) {
        const float xy   = acc[i][j][r];
        const float By   = fmaf(negc, ysv[j], 1.f);
        const float P    = Bc * By;
        const float den2 = fmaf(c2xs2, ysv[j], fmaf(n4c, xy, 2.f));   // 2*den
        const float wv   = fmaf(den2, __builtin_amdgcn_rcpf(P), -1.f);
        const float t2   = fmaxf(fmaf(wv, wv, -1.f), 0.f);
        const float W    = wv + __builtin_amdgcn_sqrtf(t2);
        const float lg   = __builtin_amdgcn_logf(W);                  // log2
        s += __builtin_amdgcn_exp2f(fmaf(-inv, lg, bv[j]));
      }
      s += __shfl_xor(s, 1, 64);
      s += __shfl_xor(s, 2, 64);
      s += __shfl_xor(s, 4, 64);
      s += __shfl_xor(s, 8, 64);
      if (l15 == 0) partials[(long)grow * NCHUNK + (bn * 2 + wc)] = s;
    }
  }
}

// ---------- per-row LSE (no atomics) ----------
__global__ __launch_bounds__(128) void lse_row_kernel(
    const float* __restrict__ partials, const float* __restrict__ tgtl,
    float* __restrict__ rowloss)
{
  const int b = blockIdx.x;
  const int tid = threadIdx.x;
  float s = 0.f;
  for (int i = tid; i < NCHUNK; i += 128) s += partials[(long)b * NCHUNK + i];
  #pragma unroll
  for (int m = 1; m < 64; m <<= 1) s += __shfl_xor(s, m, 64);
  __shared__ float red[2];
  if ((tid & 63) == 0) red[tid >> 6] = s;
  __syncthreads();
  if (tid == 0) rowloss[b] = logf(red[0] + red[1]) - tgtl[b];
}

// ---------- deterministic final mean: one block, no atomics ----------
__global__ __launch_bounds__(256) void final_sum_kernel(
    const float* __restrict__ rowloss, float* __restrict__ out)
{
  const int tid = threadIdx.x;
  float s = rowloss[tid] + rowloss[tid + 256] + rowloss[tid + 512] + rowloss[tid + 768];
  #pragma unroll
  for (int m = 1; m < 64; m <<= 1) s += __shfl_xor(s, m, 64);
  __shared__ float red[4];
  if ((tid & 63) == 0) red[tid >> 6] = s;
  __syncthreads();
  if (tid == 0) out[0] = (red[0] + red[1] + red[2] + red[3]) * (1.0f / (float)NB);
}

// ---------- launch ----------
extern "C" void kernel_launch(void* const* d_in, const int* in_sizes, int n_in,
                              void* d_out, int out_size, void* d_ws, size_t ws_size,
                              hipStream_t stream) {
  const float* q    = (const float*)d_in[0];
  const float* cand = (const float*)d_in[1];
  const float* bias = (const float*)d_in[2];
  const float* curv = (const float*)d_in[3];
  const int*   tgt  = (const int*)d_in[4];
  float* out = (float*)d_out;

  char* ws = (char*)d_ws;
  unsigned short* cb = (unsigned short*)(ws);                 // 41,025,536
  unsigned short* qb = (unsigned short*)(ws + 41025536);      //  1,048,576
  float*  ysq        = (float*) (ws + 42074112);              //    160,256
  float*  b2         = (float*) (ws + 42234368);              //    160,256
  float4* rcst       = (float4*)(ws + 42394624);              //     16,384
  float*  tgtl       = (float*) (ws + 42411008);              //      4,096
  float*  rowloss    = (float*) (ws + 42415104);              //      4,096
  float*  partials   = (float*) (ws + 42419200);              //  2,564,096 -> end 44,983,296

  prep_all_kernel<<<NPAD / 4, 256, 0, stream>>>(q, cand, bias, curv, tgt,
                                                qb, cb, ysq, rcst, b2, tgtl);
  gemm_epi_kernel<<<2504, 256, 0, stream>>>(qb, cb, rcst, ysq, b2, partials);
  lse_row_kernel<<<NB, 128, 0, stream>>>(partials, tgtl, rowloss);
  final_sum_kernel<<<1, 256, 0, stream>>>(rowloss, out);
}